// Round 2
// baseline (3414.214 us; speedup 1.0000x reference)
//
#include <hip/hip_runtime.h>
#include <hip/hip_bf16.h>

typedef float f32x4 __attribute__((ext_vector_type(4)));
typedef __bf16 bf16x8 __attribute__((ext_vector_type(8)));
typedef unsigned short u16;

#define T_TOK 4096
#define DIMK 2048
#define INTERN 1024
#define NEXP 32
#define NTOPK 6
#define NGRP 8
#define NTOPG 4
#define SINTER 2048

// ---------------- cast x fp32 -> bf16 ----------------
__global__ __launch_bounds__(256) void cast_x_kernel(const float* __restrict__ in, u16* __restrict__ out) {
    int i = (blockIdx.x * 256 + threadIdx.x) * 8;
    const float4* p = reinterpret_cast<const float4*>(in + i);
    float4 a = p[0], b = p[1];
    bf16x8 v;
    v[0] = (__bf16)a.x; v[1] = (__bf16)a.y; v[2] = (__bf16)a.z; v[3] = (__bf16)a.w;
    v[4] = (__bf16)b.x; v[5] = (__bf16)b.y; v[6] = (__bf16)b.z; v[7] = (__bf16)b.w;
    *reinterpret_cast<bf16x8*>(out + i) = v;
}

// ---------------- gate: softmax + group top-4 + top-6, build expert lists ----------------
__global__ __launch_bounds__(64) void gate_kernel(const float* __restrict__ x, const float* __restrict__ gw,
                                                  int* __restrict__ counts, int* __restrict__ ids,
                                                  float* __restrict__ wgts) {
    const int t = blockIdx.x;
    const int lane = threadIdx.x;
    __shared__ float logits[NEXP];
    const float4* xr = reinterpret_cast<const float4*>(x + (size_t)t * DIMK);
    for (int e = 0; e < NEXP; ++e) {
        const float4* gr = reinterpret_cast<const float4*>(gw + (size_t)e * DIMK);
        float acc = 0.f;
#pragma unroll
        for (int i = 0; i < DIMK / 4 / 64; ++i) {
            float4 xv = xr[lane + i * 64];
            float4 gv = gr[lane + i * 64];
            acc += xv.x * gv.x + xv.y * gv.y + xv.z * gv.z + xv.w * gv.w;
        }
#pragma unroll
        for (int s = 32; s; s >>= 1) acc += __shfl_xor(acc, s);
        if (lane == 0) logits[e] = acc;
    }
    if (lane != 0) return;
    // serial routing on lane 0 (all arrays statically indexed -> registers)
    float sc[NEXP];
#pragma unroll
    for (int e = 0; e < NEXP; ++e) sc[e] = logits[e];
    float mx = sc[0];
#pragma unroll
    for (int e = 1; e < NEXP; ++e) mx = fmaxf(mx, sc[e]);
    float ssum = 0.f;
#pragma unroll
    for (int e = 0; e < NEXP; ++e) { sc[e] = __expf(sc[e] - mx); ssum += sc[e]; }
    const float inv = 1.f / ssum;   // scores = sc * inv; scaling doesn't change argmax order
    float gsc[NGRP];
#pragma unroll
    for (int g = 0; g < NGRP; ++g) {
        float m2 = sc[g * 4];
#pragma unroll
        for (int j = 1; j < 4; ++j) m2 = fmaxf(m2, sc[g * 4 + j]);
        gsc[g] = m2;
    }
    int gsel = 0;
    for (int r = 0; r < NTOPG; ++r) {
        float bv = -1.f; int bi = 0;
#pragma unroll
        for (int g = 0; g < NGRP; ++g) {
            bool c = (((gsel >> g) & 1) == 0) && (gsc[g] > bv);
            bv = c ? gsc[g] : bv; bi = c ? g : bi;
        }
        gsel |= (1 << bi);
    }
    float msk[NEXP];
#pragma unroll
    for (int e = 0; e < NEXP; ++e) msk[e] = ((gsel >> (e >> 2)) & 1) ? sc[e] : -1.f;
    for (int r = 0; r < NTOPK; ++r) {
        float bv = -3.f; int bi = 0;
#pragma unroll
        for (int e = 0; e < NEXP; ++e) {
            bool c = msk[e] > bv;
            bv = c ? msk[e] : bv; bi = c ? e : bi;
        }
#pragma unroll
        for (int e = 0; e < NEXP; ++e) if (e == bi) msk[e] = -2.f;
        float w = bv * inv;  // ROUTE_SCALE = 1, softmax path: no renorm
        int slot = atomicAdd(&counts[bi], 1);
        ids[bi * T_TOK + slot] = t;
        wgts[bi * T_TOK + slot] = w;
    }
}

// ---------------- exclusive scan of counts (32 values) ----------------
__global__ void scan_kernel(const int* __restrict__ counts, int* __restrict__ hoff) {
    if (threadIdx.x == 0) {
        int o = 0;
        for (int e = 0; e < NEXP; ++e) { hoff[e] = o; o += counts[e]; }
    }
}

// ---------------- GEMM1: H = silu(A*Wg) * (A*Wu), A bf16 gathered rows, W fp32 [K,N] ----------------
// 128x128 tile, BK=32, 4 waves (2x2), 16x16x32 bf16 MFMA. LDS stride 40 bf16 (80B).
// A staging: each thread covers 16 bf16 (row ar, k-range akh*16..akh*16+15) -> full 128x32 coverage.
template <bool GATHER, int KK, int NN>
__global__ __launch_bounds__(256, 2) void ffn_in_kernel(
    const u16* __restrict__ Abase, const float* __restrict__ Wg, const float* __restrict__ Wu,
    u16* __restrict__ Hout,
    const int* __restrict__ counts, const int* __restrict__ ids, const int* __restrict__ hoff,
    int Mshared) {
    __shared__ u16 Alds[128 * 40];
    __shared__ u16 Bglds[128 * 40];
    __shared__ u16 Bulds[128 * 40];

    const int e = blockIdx.z;
    const int bm = blockIdx.x, bn = blockIdx.y;
    int M, hbase;
    const float *wg, *wu;
    if (GATHER) {
        M = counts[e];
        if (bm * 128 >= M) return;
        hbase = hoff[e];
        wg = Wg + (size_t)e * KK * NN;
        wu = Wu + (size_t)e * KK * NN;
    } else {
        M = Mshared; hbase = 0; wg = Wg; wu = Wu;
        if (bm * 128 >= M) return;
    }
    const int tid = threadIdx.x;
    // A staging: thread -> (row, 16-elem k-chunk)
    const int ar = tid & 127, akh = tid >> 7;
    const int arow = bm * 128 + ar;
    int tok;
    if (GATHER) { int cr = arow < M ? arow : (M - 1); tok = ids[e * T_TOK + cr]; }
    else tok = arow;
    const u16* aptr = Abase + (size_t)tok * KK + akh * 16;
    const int awo = ar * 40 + akh * 16;
    // B staging: thread -> (col n, k-range of 16); 16 coalesced dword loads along k, 2x ds_write_b128
    const int bnl = tid & 127, bkh = tid >> 7;
    const float* pg = wg + (size_t)(bkh * 16) * NN + bn * 128 + bnl;
    const float* pu = wu + (size_t)(bkh * 16) * NN + bn * 128 + bnl;
    const int bwo = bnl * 40 + bkh * 16;

    const int lane = tid & 63, wid = tid >> 6;
    const int wr = wid >> 1, wc = wid & 1;
    const int l15 = lane & 15, lk = lane >> 4;

    f32x4 accg[4][4], accu[4][4];
#pragma unroll
    for (int m = 0; m < 4; ++m)
#pragma unroll
        for (int n = 0; n < 4; ++n) {
            accg[m][n] = {0.f, 0.f, 0.f, 0.f};
            accu[m][n] = {0.f, 0.f, 0.f, 0.f};
        }

    for (int k0 = 0; k0 < KK; k0 += 32) {
        bf16x8 a0 = *reinterpret_cast<const bf16x8*>(aptr);
        bf16x8 a1 = *reinterpret_cast<const bf16x8*>(aptr + 8);
        *reinterpret_cast<bf16x8*>(&Alds[awo]) = a0;
        *reinterpret_cast<bf16x8*>(&Alds[awo + 8]) = a1;
        bf16x8 v0, v1;
#pragma unroll
        for (int j = 0; j < 8; ++j) v0[j] = (__bf16)pg[(size_t)j * NN];
#pragma unroll
        for (int j = 0; j < 8; ++j) v1[j] = (__bf16)pg[(size_t)(j + 8) * NN];
        *reinterpret_cast<bf16x8*>(&Bglds[bwo]) = v0;
        *reinterpret_cast<bf16x8*>(&Bglds[bwo + 8]) = v1;
#pragma unroll
        for (int j = 0; j < 8; ++j) v0[j] = (__bf16)pu[(size_t)j * NN];
#pragma unroll
        for (int j = 0; j < 8; ++j) v1[j] = (__bf16)pu[(size_t)(j + 8) * NN];
        *reinterpret_cast<bf16x8*>(&Bulds[bwo]) = v0;
        *reinterpret_cast<bf16x8*>(&Bulds[bwo + 8]) = v1;

        aptr += 32;
        pg += (size_t)32 * NN;
        pu += (size_t)32 * NN;

        __syncthreads();
        bf16x8 a[4], bg[4], bu[4];
#pragma unroll
        for (int m = 0; m < 4; ++m) a[m] = *reinterpret_cast<const bf16x8*>(&Alds[(wr * 64 + m * 16 + l15) * 40 + lk * 8]);
#pragma unroll
        for (int n = 0; n < 4; ++n) bg[n] = *reinterpret_cast<const bf16x8*>(&Bglds[(wc * 64 + n * 16 + l15) * 40 + lk * 8]);
#pragma unroll
        for (int n = 0; n < 4; ++n) bu[n] = *reinterpret_cast<const bf16x8*>(&Bulds[(wc * 64 + n * 16 + l15) * 40 + lk * 8]);
#pragma unroll
        for (int m = 0; m < 4; ++m)
#pragma unroll
            for (int n = 0; n < 4; ++n) {
                accg[m][n] = __builtin_amdgcn_mfma_f32_16x16x32_bf16(a[m], bg[n], accg[m][n], 0, 0, 0);
                accu[m][n] = __builtin_amdgcn_mfma_f32_16x16x32_bf16(a[m], bu[n], accu[m][n], 0, 0, 0);
            }
        __syncthreads();
    }
    // epilogue: h = silu(g)*u, store bf16
#pragma unroll
    for (int m = 0; m < 4; ++m) {
#pragma unroll
        for (int r = 0; r < 4; ++r) {
            int rowl = wr * 64 + m * 16 + lk * 4 + r;
            int grow = bm * 128 + rowl;
            if (grow < M) {
#pragma unroll
                for (int n = 0; n < 4; ++n) {
                    float g = accg[m][n][r], u = accu[m][n][r];
                    float h = g / (1.f + __expf(-g)) * u;
                    int col = bn * 128 + wc * 64 + n * 16 + l15;
                    __bf16 hb = (__bf16)h;
                    Hout[(size_t)(hbase + grow) * NN + col] = __builtin_bit_cast(u16, hb);
                }
            }
        }
    }
}

// ---------------- GEMM2: Y = H * Wd; expert: atomicAdd(out[tok], y*w); shared: plain store ----------------
template <bool ATOMIC, int KK, int NN>
__global__ __launch_bounds__(256, 2) void ffn_out_kernel(
    const u16* __restrict__ Hbase, const float* __restrict__ Wd, float* __restrict__ out,
    const int* __restrict__ counts, const int* __restrict__ ids, const int* __restrict__ hoff,
    const float* __restrict__ wgts, int Mshared) {
    __shared__ u16 Alds[128 * 40];
    __shared__ u16 Blds[128 * 40];

    const int e = blockIdx.z;
    const int bm = blockIdx.x, bn = blockIdx.y;
    int M;
    const u16* A;
    const float* wdp;
    if (ATOMIC) {
        M = counts[e];
        if (bm * 128 >= M) return;
        A = Hbase + (size_t)hoff[e] * KK;
        wdp = Wd + (size_t)e * KK * NN;
    } else {
        M = Mshared; A = Hbase; wdp = Wd;
        if (bm * 128 >= M) return;
    }
    const int tid = threadIdx.x;
    const int ar = tid & 127, akh = tid >> 7;
    const int arow = bm * 128 + ar;
    const int cr = arow < M ? arow : (M - 1);
    const u16* aptr = A + (size_t)cr * KK + akh * 16;
    const int awo = ar * 40 + akh * 16;
    const int bnl = tid & 127, bkh = tid >> 7;
    const float* pb = wdp + (size_t)(bkh * 16) * NN + bn * 128 + bnl;
    const int bwo = bnl * 40 + bkh * 16;

    const int lane = tid & 63, wid = tid >> 6;
    const int wr = wid >> 1, wc = wid & 1;
    const int l15 = lane & 15, lk = lane >> 4;

    f32x4 acc[4][4];
#pragma unroll
    for (int m = 0; m < 4; ++m)
#pragma unroll
        for (int n = 0; n < 4; ++n) acc[m][n] = {0.f, 0.f, 0.f, 0.f};

    for (int k0 = 0; k0 < KK; k0 += 32) {
        bf16x8 a0 = *reinterpret_cast<const bf16x8*>(aptr);
        bf16x8 a1 = *reinterpret_cast<const bf16x8*>(aptr + 8);
        *reinterpret_cast<bf16x8*>(&Alds[awo]) = a0;
        *reinterpret_cast<bf16x8*>(&Alds[awo + 8]) = a1;
        bf16x8 v0, v1;
#pragma unroll
        for (int j = 0; j < 8; ++j) v0[j] = (__bf16)pb[(size_t)j * NN];
#pragma unroll
        for (int j = 0; j < 8; ++j) v1[j] = (__bf16)pb[(size_t)(j + 8) * NN];
        *reinterpret_cast<bf16x8*>(&Blds[bwo]) = v0;
        *reinterpret_cast<bf16x8*>(&Blds[bwo + 8]) = v1;

        aptr += 32;
        pb += (size_t)32 * NN;

        __syncthreads();
        bf16x8 a[4], b[4];
#pragma unroll
        for (int m = 0; m < 4; ++m) a[m] = *reinterpret_cast<const bf16x8*>(&Alds[(wr * 64 + m * 16 + l15) * 40 + lk * 8]);
#pragma unroll
        for (int n = 0; n < 4; ++n) b[n] = *reinterpret_cast<const bf16x8*>(&Blds[(wc * 64 + n * 16 + l15) * 40 + lk * 8]);
#pragma unroll
        for (int m = 0; m < 4; ++m)
#pragma unroll
            for (int n = 0; n < 4; ++n)
                acc[m][n] = __builtin_amdgcn_mfma_f32_16x16x32_bf16(a[m], b[n], acc[m][n], 0, 0, 0);
        __syncthreads();
    }
#pragma unroll
    for (int m = 0; m < 4; ++m) {
#pragma unroll
        for (int r = 0; r < 4; ++r) {
            int rowl = wr * 64 + m * 16 + lk * 4 + r;
            int grow = bm * 128 + rowl;
            if (grow < M) {
                if (ATOMIC) {
                    int tok = ids[e * T_TOK + grow];
                    float w = wgts[e * T_TOK + grow];
#pragma unroll
                    for (int n = 0; n < 4; ++n) {
                        int col = bn * 128 + wc * 64 + n * 16 + l15;
                        atomicAdd(&out[(size_t)tok * NN + col], acc[m][n][r] * w);
                    }
                } else {
#pragma unroll
                    for (int n = 0; n < 4; ++n) {
                        int col = bn * 128 + wc * 64 + n * 16 + l15;
                        out[(size_t)grow * NN + col] = acc[m][n][r];
                    }
                }
            }
        }
    }
}

extern "C" void kernel_launch(void* const* d_in, const int* in_sizes, int n_in,
                              void* d_out, int out_size, void* d_ws, size_t ws_size,
                              hipStream_t stream) {
    const float* x = (const float*)d_in[0];
    const float* gate_w = (const float*)d_in[1];
    const float* wg = (const float*)d_in[2];
    const float* wu = (const float*)d_in[3];
    const float* wd = (const float*)d_in[4];
    const float* swg = (const float*)d_in[5];
    const float* swu = (const float*)d_in[6];
    const float* swd = (const float*)d_in[7];
    float* out = (float*)d_out;

    char* ws = (char*)d_ws;
    size_t off = 0;
    auto alloc = [&](size_t bytes) {
        void* p = ws + off;
        off = (off + bytes + 255) & ~(size_t)255;
        return p;
    };
    u16* xb = (u16*)alloc((size_t)T_TOK * DIMK * 2);                    // 16.8 MB
    u16* H = (u16*)alloc((size_t)T_TOK * NTOPK * INTERN * 2);           // 50.3 MB
    u16* Hs = (u16*)alloc((size_t)T_TOK * SINTER * 2);                  // 16.8 MB
    int* ids = (int*)alloc((size_t)NEXP * T_TOK * 4);
    float* wgts = (float*)alloc((size_t)NEXP * T_TOK * 4);
    int* counts = (int*)alloc(NEXP * 4);
    int* hoff = (int*)alloc(NEXP * 4);

    hipMemsetAsync(counts, 0, NEXP * 4, stream);
    cast_x_kernel<<<(T_TOK * DIMK) / (256 * 8), 256, 0, stream>>>(x, xb);
    gate_kernel<<<T_TOK, 64, 0, stream>>>(x, gate_w, counts, ids, wgts);
    scan_kernel<<<1, 64, 0, stream>>>(counts, hoff);
    // expert GEMM1 (gather + fused silu*up), K=2048, N=1024
    ffn_in_kernel<true, DIMK, INTERN><<<dim3(32, INTERN / 128, NEXP), 256, 0, stream>>>(
        xb, wg, wu, H, counts, ids, hoff, 0);
    // shared GEMM1, K=2048, N=2048
    ffn_in_kernel<false, DIMK, SINTER><<<dim3(T_TOK / 128, SINTER / 128, 1), 256, 0, stream>>>(
        xb, swg, swu, Hs, nullptr, nullptr, nullptr, T_TOK);
    // shared GEMM2 writes d_out (full overwrite), K=2048, N=2048
    ffn_out_kernel<false, SINTER, DIMK><<<dim3(T_TOK / 128, DIMK / 128, 1), 256, 0, stream>>>(
        Hs, swd, out, nullptr, nullptr, nullptr, nullptr, T_TOK);
    // expert GEMM2 atomic-accumulates, K=1024, N=2048
    ffn_out_kernel<true, INTERN, DIMK><<<dim3(32, DIMK / 128, NEXP), 256, 0, stream>>>(
        H, wd, out, counts, ids, hoff, wgts, 0);
}

// Round 3
// 2537.062 us; speedup vs baseline: 1.3457x; 1.3457x over previous
//
#include <hip/hip_runtime.h>
#include <hip/hip_bf16.h>

typedef float f32x4 __attribute__((ext_vector_type(4)));
typedef __bf16 bf16x8 __attribute__((ext_vector_type(8)));
typedef unsigned short u16;

#define T_TOK 4096
#define DIMK 2048
#define INTERN 1024
#define NEXP 32
#define NTOPK 6
#define NGRP 8
#define NTOPG 4
#define SINTER 2048

// async global->LDS 16B: per-lane global src, wave-uniform LDS base + lane*16
__device__ __forceinline__ void glds16(const void* g, void* l) {
    auto* gp = (const __attribute__((address_space(1))) int*)(g);
    auto* lp = (__attribute__((address_space(3))) int*)(l);
    __builtin_amdgcn_global_load_lds(gp, lp, 16, 0, 0);
}

// ---------------- cast x fp32 -> bf16 ----------------
__global__ __launch_bounds__(256) void cast_x_kernel(const float* __restrict__ in, u16* __restrict__ out) {
    int i = (blockIdx.x * 256 + threadIdx.x) * 8;
    const float4* p = reinterpret_cast<const float4*>(in + i);
    float4 a = p[0], b = p[1];
    bf16x8 v;
    v[0] = (__bf16)a.x; v[1] = (__bf16)a.y; v[2] = (__bf16)a.z; v[3] = (__bf16)a.w;
    v[4] = (__bf16)b.x; v[5] = (__bf16)b.y; v[6] = (__bf16)b.z; v[7] = (__bf16)b.w;
    *reinterpret_cast<bf16x8*>(out + i) = v;
}

// ---------------- transpose+convert: fp32 [R][C] -> bf16 [C][R], batched over z ----------------
// 64x64 tile via LDS fp32 [64][65] (pitch 65 => bank=(r+c)%32: both phases ~2-way = free).
template <int R, int C>
__global__ __launch_bounds__(256) void transpose_cvt_kernel(const float* __restrict__ in, u16* __restrict__ out) {
    __shared__ float tile[64 * 65];
    const int t = threadIdx.x;
    const size_t bofs = (size_t)blockIdx.z * R * C;
    const float* ib = in + bofs;
    u16* ob = out + bofs;
    const int r0 = blockIdx.y * 64, c0 = blockIdx.x * 64;
    // phase 1: load float4 along C, scatter 4 scalars into LDS [r][c]
    {
        const int c4 = (t & 15) * 4;
#pragma unroll
        for (int i = 0; i < 4; ++i) {
            const int r = (t >> 4) + i * 16;
            float4 v = *reinterpret_cast<const float4*>(&ib[(size_t)(r0 + r) * C + c0 + c4]);
            tile[r * 65 + c4 + 0] = v.x;
            tile[r * 65 + c4 + 1] = v.y;
            tile[r * 65 + c4 + 2] = v.z;
            tile[r * 65 + c4 + 3] = v.w;
        }
    }
    __syncthreads();
    // phase 2: read 16 r-consecutive scalars for fixed c, pack 2x bf16x8, wide store
    {
        const int c = t >> 2;
        const int rj = (t & 3) * 16;
        bf16x8 v0, v1;
#pragma unroll
        for (int j = 0; j < 8; ++j) v0[j] = (__bf16)tile[(rj + j) * 65 + c];
#pragma unroll
        for (int j = 0; j < 8; ++j) v1[j] = (__bf16)tile[(rj + 8 + j) * 65 + c];
        u16* po = &ob[(size_t)(c0 + c) * R + r0 + rj];
        *reinterpret_cast<bf16x8*>(po) = v0;
        *reinterpret_cast<bf16x8*>(po + 8) = v1;
    }
}

// ---------------- gate: softmax + group top-4 + top-6, build expert lists ----------------
__global__ __launch_bounds__(64) void gate_kernel(const float* __restrict__ x, const float* __restrict__ gw,
                                                  int* __restrict__ counts, int* __restrict__ ids,
                                                  float* __restrict__ wgts) {
    const int t = blockIdx.x;
    const int lane = threadIdx.x;
    __shared__ float logits[NEXP];
    const float4* xr = reinterpret_cast<const float4*>(x + (size_t)t * DIMK);
    for (int e = 0; e < NEXP; ++e) {
        const float4* gr = reinterpret_cast<const float4*>(gw + (size_t)e * DIMK);
        float acc = 0.f;
#pragma unroll
        for (int i = 0; i < DIMK / 4 / 64; ++i) {
            float4 xv = xr[lane + i * 64];
            float4 gv = gr[lane + i * 64];
            acc += xv.x * gv.x + xv.y * gv.y + xv.z * gv.z + xv.w * gv.w;
        }
#pragma unroll
        for (int s = 32; s; s >>= 1) acc += __shfl_xor(acc, s);
        if (lane == 0) logits[e] = acc;
    }
    if (lane != 0) return;
    float sc[NEXP];
#pragma unroll
    for (int e = 0; e < NEXP; ++e) sc[e] = logits[e];
    float mx = sc[0];
#pragma unroll
    for (int e = 1; e < NEXP; ++e) mx = fmaxf(mx, sc[e]);
    float ssum = 0.f;
#pragma unroll
    for (int e = 0; e < NEXP; ++e) { sc[e] = __expf(sc[e] - mx); ssum += sc[e]; }
    const float inv = 1.f / ssum;
    float gsc[NGRP];
#pragma unroll
    for (int g = 0; g < NGRP; ++g) {
        float m2 = sc[g * 4];
#pragma unroll
        for (int j = 1; j < 4; ++j) m2 = fmaxf(m2, sc[g * 4 + j]);
        gsc[g] = m2;
    }
    int gsel = 0;
    for (int r = 0; r < NTOPG; ++r) {
        float bv = -1.f; int bi = 0;
#pragma unroll
        for (int g = 0; g < NGRP; ++g) {
            bool c = (((gsel >> g) & 1) == 0) && (gsc[g] > bv);
            bv = c ? gsc[g] : bv; bi = c ? g : bi;
        }
        gsel |= (1 << bi);
    }
    float msk[NEXP];
#pragma unroll
    for (int e = 0; e < NEXP; ++e) msk[e] = ((gsel >> (e >> 2)) & 1) ? sc[e] : -1.f;
    for (int r = 0; r < NTOPK; ++r) {
        float bv = -3.f; int bi = 0;
#pragma unroll
        for (int e = 0; e < NEXP; ++e) {
            bool c = msk[e] > bv;
            bv = c ? msk[e] : bv; bi = c ? e : bi;
        }
#pragma unroll
        for (int e = 0; e < NEXP; ++e) if (e == bi) msk[e] = -2.f;
        float w = bv * inv;
        int slot = atomicAdd(&counts[bi], 1);
        ids[bi * T_TOK + slot] = t;
        wgts[bi * T_TOK + slot] = w;
    }
}

__global__ void scan_kernel(const int* __restrict__ counts, int* __restrict__ hoff) {
    if (threadIdx.x == 0) {
        int o = 0;
        for (int e = 0; e < NEXP; ++e) { hoff[e] = o; o += counts[e]; }
    }
}

// ---------------- GEMM1: H = silu(A*WgT^T) * (A*WuT^T); all operands bf16 row-major [.][K] ----------------
// 128x128 tile, BK=32, 4 waves 2x2, global_load_lds staging, linear LDS [128][32].
template <bool GATHER, int KK, int NN>
__global__ __launch_bounds__(256, 2) void ffn_in_kernel(
    const u16* __restrict__ Abase, const u16* __restrict__ BgT, const u16* __restrict__ BuT,
    u16* __restrict__ Hout,
    const int* __restrict__ counts, const int* __restrict__ ids, const int* __restrict__ hoff,
    int Mshared) {
    __shared__ u16 Alds[128 * 32];
    __shared__ u16 Bglds[128 * 32];
    __shared__ u16 Bulds[128 * 32];

    const int e = blockIdx.z;
    const int bm = blockIdx.x, bn = blockIdx.y;
    int M, hbase;
    const u16 *bg0, *bu0;
    if (GATHER) {
        M = counts[e];
        if (bm * 128 >= M) return;
        hbase = hoff[e];
        bg0 = BgT + (size_t)e * NN * KK;
        bu0 = BuT + (size_t)e * NN * KK;
    } else {
        M = Mshared; hbase = 0; bg0 = BgT; bu0 = BuT;
        if (bm * 128 >= M) return;
    }
    const int tid = threadIdx.x;
    const int lane = tid & 63, wid = tid >> 6;
    const int ksl = (lane & 3) * 8;  // k-slot within 32-wide k-tile

    const u16* aSrc[2];
    const u16* gSrc[2];
    const u16* uSrc[2];
    int ldsOff[2];
#pragma unroll
    for (int i = 0; i < 2; ++i) {
        const int ci = wid * 2 + i;              // chunk 0..7, 16 rows each
        const int row = ci * 16 + (lane >> 2);
        const int grow = bm * 128 + row;
        const int cr = grow < M ? grow : (M - 1);
        const int tok = GATHER ? ids[e * T_TOK + cr] : cr;
        aSrc[i] = Abase + (size_t)tok * KK + ksl;
        const int nrow = bn * 128 + row;
        gSrc[i] = bg0 + (size_t)nrow * KK + ksl;
        uSrc[i] = bu0 + (size_t)nrow * KK + ksl;
        ldsOff[i] = ci * 512;                    // u16 elems (1024B per chunk)
    }

    const int wr = wid >> 1, wc = wid & 1;
    const int l15 = lane & 15, lk = lane >> 4;

    f32x4 accg[4][4], accu[4][4];
#pragma unroll
    for (int m = 0; m < 4; ++m)
#pragma unroll
        for (int n = 0; n < 4; ++n) {
            accg[m][n] = {0.f, 0.f, 0.f, 0.f};
            accu[m][n] = {0.f, 0.f, 0.f, 0.f};
        }

    for (int k0 = 0; k0 < KK; k0 += 32) {
#pragma unroll
        for (int i = 0; i < 2; ++i) {
            glds16(aSrc[i] + k0, &Alds[ldsOff[i]]);
            glds16(gSrc[i] + k0, &Bglds[ldsOff[i]]);
            glds16(uSrc[i] + k0, &Bulds[ldsOff[i]]);
        }
        __syncthreads();
        bf16x8 a[4], bg[4], bu[4];
#pragma unroll
        for (int m = 0; m < 4; ++m) a[m] = *reinterpret_cast<const bf16x8*>(&Alds[(wr * 64 + m * 16 + l15) * 32 + lk * 8]);
#pragma unroll
        for (int n = 0; n < 4; ++n) bg[n] = *reinterpret_cast<const bf16x8*>(&Bglds[(wc * 64 + n * 16 + l15) * 32 + lk * 8]);
#pragma unroll
        for (int n = 0; n < 4; ++n) bu[n] = *reinterpret_cast<const bf16x8*>(&Bulds[(wc * 64 + n * 16 + l15) * 32 + lk * 8]);
#pragma unroll
        for (int m = 0; m < 4; ++m)
#pragma unroll
            for (int n = 0; n < 4; ++n) {
                accg[m][n] = __builtin_amdgcn_mfma_f32_16x16x32_bf16(a[m], bg[n], accg[m][n], 0, 0, 0);
                accu[m][n] = __builtin_amdgcn_mfma_f32_16x16x32_bf16(a[m], bu[n], accu[m][n], 0, 0, 0);
            }
        __syncthreads();
    }
#pragma unroll
    for (int m = 0; m < 4; ++m) {
#pragma unroll
        for (int r = 0; r < 4; ++r) {
            int rowl = wr * 64 + m * 16 + lk * 4 + r;
            int grow = bm * 128 + rowl;
            if (grow < M) {
#pragma unroll
                for (int n = 0; n < 4; ++n) {
                    float g = accg[m][n][r], u = accu[m][n][r];
                    float h = g / (1.f + __expf(-g)) * u;
                    int col = bn * 128 + wc * 64 + n * 16 + l15;
                    __bf16 hb = (__bf16)h;
                    Hout[(size_t)(hbase + grow) * NN + col] = __builtin_bit_cast(u16, hb);
                }
            }
        }
    }
}

// ---------------- GEMM2: Y = H * WdT^T; expert: atomicAdd(out*w); shared: plain store ----------------
template <bool ATOMIC, int KK, int NN>
__global__ __launch_bounds__(256, 2) void ffn_out_kernel(
    const u16* __restrict__ Hbase, const u16* __restrict__ BdT, float* __restrict__ out,
    const int* __restrict__ counts, const int* __restrict__ ids, const int* __restrict__ hoff,
    const float* __restrict__ wgts, int Mshared) {
    __shared__ u16 Alds[128 * 32];
    __shared__ u16 Blds[128 * 32];

    const int e = blockIdx.z;
    const int bm = blockIdx.x, bn = blockIdx.y;
    int M;
    const u16* A;
    const u16* b0;
    if (ATOMIC) {
        M = counts[e];
        if (bm * 128 >= M) return;
        A = Hbase + (size_t)hoff[e] * KK;
        b0 = BdT + (size_t)e * NN * KK;
    } else {
        M = Mshared; A = Hbase; b0 = BdT;
        if (bm * 128 >= M) return;
    }
    const int tid = threadIdx.x;
    const int lane = tid & 63, wid = tid >> 6;
    const int ksl = (lane & 3) * 8;

    const u16* aSrc[2];
    const u16* bSrc[2];
    int ldsOff[2];
#pragma unroll
    for (int i = 0; i < 2; ++i) {
        const int ci = wid * 2 + i;
        const int row = ci * 16 + (lane >> 2);
        const int grow = bm * 128 + row;
        const int cr = grow < M ? grow : (M - 1);
        aSrc[i] = A + (size_t)cr * KK + ksl;
        const int nrow = bn * 128 + row;
        bSrc[i] = b0 + (size_t)nrow * KK + ksl;
        ldsOff[i] = ci * 512;
    }

    const int wr = wid >> 1, wc = wid & 1;
    const int l15 = lane & 15, lk = lane >> 4;

    f32x4 acc[4][4];
#pragma unroll
    for (int m = 0; m < 4; ++m)
#pragma unroll
        for (int n = 0; n < 4; ++n) acc[m][n] = {0.f, 0.f, 0.f, 0.f};

    for (int k0 = 0; k0 < KK; k0 += 32) {
#pragma unroll
        for (int i = 0; i < 2; ++i) {
            glds16(aSrc[i] + k0, &Alds[ldsOff[i]]);
            glds16(bSrc[i] + k0, &Blds[ldsOff[i]]);
        }
        __syncthreads();
        bf16x8 a[4], b[4];
#pragma unroll
        for (int m = 0; m < 4; ++m) a[m] = *reinterpret_cast<const bf16x8*>(&Alds[(wr * 64 + m * 16 + l15) * 32 + lk * 8]);
#pragma unroll
        for (int n = 0; n < 4; ++n) b[n] = *reinterpret_cast<const bf16x8*>(&Blds[(wc * 64 + n * 16 + l15) * 32 + lk * 8]);
#pragma unroll
        for (int m = 0; m < 4; ++m)
#pragma unroll
            for (int n = 0; n < 4; ++n)
                acc[m][n] = __builtin_amdgcn_mfma_f32_16x16x32_bf16(a[m], b[n], acc[m][n], 0, 0, 0);
        __syncthreads();
    }
#pragma unroll
    for (int m = 0; m < 4; ++m) {
#pragma unroll
        for (int r = 0; r < 4; ++r) {
            int rowl = wr * 64 + m * 16 + lk * 4 + r;
            int grow = bm * 128 + rowl;
            if (grow < M) {
                if (ATOMIC) {
                    int tok = ids[e * T_TOK + grow];
                    float w = wgts[e * T_TOK + grow];
#pragma unroll
                    for (int n = 0; n < 4; ++n) {
                        int col = bn * 128 + wc * 64 + n * 16 + l15;
                        atomicAdd(&out[(size_t)tok * NN + col], acc[m][n][r] * w);
                    }
                } else {
#pragma unroll
                    for (int n = 0; n < 4; ++n) {
                        int col = bn * 128 + wc * 64 + n * 16 + l15;
                        out[(size_t)grow * NN + col] = acc[m][n][r];
                    }
                }
            }
        }
    }
}

extern "C" void kernel_launch(void* const* d_in, const int* in_sizes, int n_in,
                              void* d_out, int out_size, void* d_ws, size_t ws_size,
                              hipStream_t stream) {
    const float* x = (const float*)d_in[0];
    const float* gate_w = (const float*)d_in[1];
    const float* wg = (const float*)d_in[2];
    const float* wu = (const float*)d_in[3];
    const float* wd = (const float*)d_in[4];
    const float* swg = (const float*)d_in[5];
    const float* swu = (const float*)d_in[6];
    const float* swd = (const float*)d_in[7];
    float* out = (float*)d_out;

    char* ws = (char*)d_ws;
    size_t off = 0;
    auto alloc = [&](size_t bytes) {
        void* p = ws + off;
        off = (off + bytes + 255) & ~(size_t)255;
        return p;
    };
    u16* xb = (u16*)alloc((size_t)T_TOK * DIMK * 2);                 // 16.8 MB
    u16* H = (u16*)alloc((size_t)T_TOK * NTOPK * INTERN * 2);        // 50.3 MB
    u16* Hs = (u16*)alloc((size_t)T_TOK * SINTER * 2);               // 16.8 MB
    int* ids = (int*)alloc((size_t)NEXP * T_TOK * 4);
    float* wgts = (float*)alloc((size_t)NEXP * T_TOK * 4);
    int* counts = (int*)alloc(NEXP * 4);
    int* hoff = (int*)alloc(NEXP * 4);
    u16* swgT = (u16*)alloc((size_t)SINTER * DIMK * 2);              // 8.4 MB
    u16* swuT = (u16*)alloc((size_t)SINTER * DIMK * 2);              // 8.4 MB
    u16* swdT = (u16*)alloc((size_t)DIMK * SINTER * 2);              // 8.4 MB
    u16* wgT = (u16*)alloc((size_t)NEXP * INTERN * DIMK * 2);        // 134 MB
    u16* wuT = (u16*)alloc((size_t)NEXP * INTERN * DIMK * 2);        // 134 MB
    u16* wdT = wgT;  // alias: wd transpose runs AFTER expert GEMM1 consumed wgT (stream-ordered)

    hipMemsetAsync(counts, 0, NEXP * 4, stream);
    cast_x_kernel<<<(T_TOK * DIMK) / (256 * 8), 256, 0, stream>>>(x, xb);
    gate_kernel<<<T_TOK, 64, 0, stream>>>(x, gate_w, counts, ids, wgts);
    scan_kernel<<<1, 64, 0, stream>>>(counts, hoff);

    // weight transpose+convert passes: fp32 [R][C] -> bf16 [C][R]
    transpose_cvt_kernel<DIMK, SINTER><<<dim3(SINTER / 64, DIMK / 64, 1), 256, 0, stream>>>(swg, swgT);
    transpose_cvt_kernel<DIMK, SINTER><<<dim3(SINTER / 64, DIMK / 64, 1), 256, 0, stream>>>(swu, swuT);
    transpose_cvt_kernel<SINTER, DIMK><<<dim3(DIMK / 64, SINTER / 64, 1), 256, 0, stream>>>(swd, swdT);
    transpose_cvt_kernel<DIMK, INTERN><<<dim3(INTERN / 64, DIMK / 64, NEXP), 256, 0, stream>>>(wg, wgT);
    transpose_cvt_kernel<DIMK, INTERN><<<dim3(INTERN / 64, DIMK / 64, NEXP), 256, 0, stream>>>(wu, wuT);

    // expert GEMM1 (gather + fused silu*up): A=[M][2048], B=[1024][2048]
    ffn_in_kernel<true, DIMK, INTERN><<<dim3(32, INTERN / 128, NEXP), 256, 0, stream>>>(
        xb, wgT, wuT, H, counts, ids, hoff, 0);
    // shared GEMM1: A=[4096][2048], B=[2048][2048]
    ffn_in_kernel<false, DIMK, SINTER><<<dim3(T_TOK / 128, SINTER / 128, 1), 256, 0, stream>>>(
        xb, swgT, swuT, Hs, nullptr, nullptr, nullptr, T_TOK);

    // wd transpose into aliased region (expert GEMM1 done with wgT by stream order)
    transpose_cvt_kernel<INTERN, DIMK><<<dim3(DIMK / 64, INTERN / 64, NEXP), 256, 0, stream>>>(wd, wdT);

    // shared GEMM2 writes d_out (full overwrite): K=2048, N=2048
    ffn_out_kernel<false, SINTER, DIMK><<<dim3(T_TOK / 128, DIMK / 128, 1), 256, 0, stream>>>(
        Hs, swdT, out, nullptr, nullptr, nullptr, nullptr, T_TOK);
    // expert GEMM2 atomic-accumulates: K=1024, N=2048
    ffn_out_kernel<true, INTERN, DIMK><<<dim3(32, DIMK / 128, NEXP), 256, 0, stream>>>(
        H, wdT, out, counts, ids, hoff, wgts, 0);
}

// Round 4
// 1264.208 us; speedup vs baseline: 2.7007x; 2.0068x over previous
//
#include <hip/hip_runtime.h>
#include <hip/hip_bf16.h>

typedef float f32x4 __attribute__((ext_vector_type(4)));
typedef __bf16 bf16x8 __attribute__((ext_vector_type(8)));
typedef unsigned short u16;

#define T_TOK 4096
#define DIMK 2048
#define INTERN 1024
#define NEXP 32
#define NTOPK 6
#define NGRP 8
#define NTOPG 4
#define SINTER 2048
#define MAXPADROWS 28672  // 24576 + 32*127 rounded up

// async global->LDS 16B
__device__ __forceinline__ void glds16(const void* g, void* l) {
    auto* gp = (const __attribute__((address_space(1))) int*)(g);
    auto* lp = (__attribute__((address_space(3))) int*)(l);
    __builtin_amdgcn_global_load_lds(gp, lp, 16, 0, 0);
}

// Tiled layout for a [Rows][K] bf16 matrix: chunk = (rowblk, kb) of 128x32 elems (8KB),
// chunks ordered kb-fastest within rowblk; inside chunk: elem = (row&127)*32 + (k&31).
// A wave's glds16 stage of 16 rows is then 1KB contiguous.

// ---------------- cast x fp32 -> bf16 tiled ----------------
__global__ __launch_bounds__(256) void cast_x_tiled_kernel(const float* __restrict__ in, u16* __restrict__ out) {
    int g = (blockIdx.x * 256 + threadIdx.x) * 8;
    int row = g >> 11, k = g & 2047;
    const float4* p = reinterpret_cast<const float4*>(in + g);
    float4 a = p[0], b = p[1];
    bf16x8 v;
    v[0] = (__bf16)a.x; v[1] = (__bf16)a.y; v[2] = (__bf16)a.z; v[3] = (__bf16)a.w;
    v[4] = (__bf16)b.x; v[5] = (__bf16)b.y; v[6] = (__bf16)b.z; v[7] = (__bf16)b.w;
    size_t dst = (size_t)(row >> 7) * (128 * 2048) + (size_t)(k >> 5) * 4096 + (row & 127) * 32 + (k & 31);
    *reinterpret_cast<bf16x8*>(out + dst) = v;
}

// ---------------- transpose+convert: fp32 [R][C] -> bf16 tiled [C-rows][R-k], batched over z ----------------
template <int R, int C>
__global__ __launch_bounds__(256) void transpose_cvt_tiled_kernel(const float* __restrict__ in, u16* __restrict__ out) {
    __shared__ float tile[64 * 65];
    const int t = threadIdx.x;
    const size_t bofs = (size_t)blockIdx.z * R * C;
    const float* ib = in + bofs;
    u16* ob = out + bofs;
    const int r0 = blockIdx.y * 64, c0 = blockIdx.x * 64;
    {
        const int c4 = (t & 15) * 4;
#pragma unroll
        for (int i = 0; i < 4; ++i) {
            const int r = (t >> 4) + i * 16;
            float4 v = *reinterpret_cast<const float4*>(&ib[(size_t)(r0 + r) * C + c0 + c4]);
            tile[r * 65 + c4 + 0] = v.x;
            tile[r * 65 + c4 + 1] = v.y;
            tile[r * 65 + c4 + 2] = v.z;
            tile[r * 65 + c4 + 3] = v.w;
        }
    }
    __syncthreads();
    {
        const int cl = t >> 2;              // local col (output row) 0..63
        const int rj = (t & 3) * 16;        // local k start
        const int n = c0 + cl;              // output row index
        const int k = r0 + rj;              // output k index
        bf16x8 v0, v1;
#pragma unroll
        for (int j = 0; j < 8; ++j) v0[j] = (__bf16)tile[(rj + j) * 65 + cl];
#pragma unroll
        for (int j = 0; j < 8; ++j) v1[j] = (__bf16)tile[(rj + 8 + j) * 65 + cl];
        size_t dst = (size_t)(n >> 7) * (128 * R) + (size_t)(k >> 5) * 4096 + (n & 127) * 32 + (k & 31);
        *reinterpret_cast<bf16x8*>(ob + dst) = v0;
        *reinterpret_cast<bf16x8*>(ob + dst + 8) = v1;
    }
}

// ---------------- gate ----------------
__global__ __launch_bounds__(64) void gate_kernel(const float* __restrict__ x, const float* __restrict__ gw,
                                                  int* __restrict__ counts, int* __restrict__ ids,
                                                  float* __restrict__ wgts) {
    const int t = blockIdx.x;
    const int lane = threadIdx.x;
    __shared__ float logits[NEXP];
    const float4* xr = reinterpret_cast<const float4*>(x + (size_t)t * DIMK);
    for (int e = 0; e < NEXP; ++e) {
        const float4* gr = reinterpret_cast<const float4*>(gw + (size_t)e * DIMK);
        float acc = 0.f;
#pragma unroll
        for (int i = 0; i < DIMK / 4 / 64; ++i) {
            float4 xv = xr[lane + i * 64];
            float4 gv = gr[lane + i * 64];
            acc += xv.x * gv.x + xv.y * gv.y + xv.z * gv.z + xv.w * gv.w;
        }
#pragma unroll
        for (int s = 32; s; s >>= 1) acc += __shfl_xor(acc, s);
        if (lane == 0) logits[e] = acc;
    }
    if (lane != 0) return;
    float sc[NEXP];
#pragma unroll
    for (int e = 0; e < NEXP; ++e) sc[e] = logits[e];
    float mx = sc[0];
#pragma unroll
    for (int e = 1; e < NEXP; ++e) mx = fmaxf(mx, sc[e]);
    float ssum = 0.f;
#pragma unroll
    for (int e = 0; e < NEXP; ++e) { sc[e] = __expf(sc[e] - mx); ssum += sc[e]; }
    const float inv = 1.f / ssum;
    float gsc[NGRP];
#pragma unroll
    for (int g = 0; g < NGRP; ++g) {
        float m2 = sc[g * 4];
#pragma unroll
        for (int j = 1; j < 4; ++j) m2 = fmaxf(m2, sc[g * 4 + j]);
        gsc[g] = m2;
    }
    int gsel = 0;
    for (int r = 0; r < NTOPG; ++r) {
        float bv = -1.f; int bi = 0;
#pragma unroll
        for (int g = 0; g < NGRP; ++g) {
            bool c = (((gsel >> g) & 1) == 0) && (gsc[g] > bv);
            bv = c ? gsc[g] : bv; bi = c ? g : bi;
        }
        gsel |= (1 << bi);
    }
    float msk[NEXP];
#pragma unroll
    for (int e = 0; e < NEXP; ++e) msk[e] = ((gsel >> (e >> 2)) & 1) ? sc[e] : -1.f;
    for (int r = 0; r < NTOPK; ++r) {
        float bv = -3.f; int bi = 0;
#pragma unroll
        for (int e = 0; e < NEXP; ++e) {
            bool c = msk[e] > bv;
            bv = c ? msk[e] : bv; bi = c ? e : bi;
        }
#pragma unroll
        for (int e = 0; e < NEXP; ++e) if (e == bi) msk[e] = -2.f;
        float w = bv * inv;
        int slot = atomicAdd(&counts[bi], 1);
        ids[bi * T_TOK + slot] = t;
        wgts[bi * T_TOK + slot] = w;
    }
}

// ---------------- scan: 128-padded exclusive offsets ----------------
__global__ void scan_kernel(const int* __restrict__ counts, int* __restrict__ poff) {
    if (threadIdx.x == 0) {
        int o = 0;
        for (int e = 0; e < NEXP; ++e) { poff[e] = o; o += (counts[e] + 127) & ~127; }
    }
}

// ---------------- gather: x fp32 rows -> per-expert compact padded tiled bf16 A ----------------
__global__ __launch_bounds__(256) void gather_a_kernel(const float* __restrict__ x, const int* __restrict__ ids,
                                                       const int* __restrict__ counts, const int* __restrict__ poff,
                                                       u16* __restrict__ At) {
    const int e = blockIdx.y, bm = blockIdx.x;
    const int M = counts[e];
    if (bm * 128 >= M) return;
    const int t = threadIdx.x;
    const int row = t >> 1, kh = (t & 1) * 16;
    const int lr = bm * 128 + row;
    const int cr = lr < M ? lr : M - 1;
    const int tok = ids[e * T_TOK + cr];
    const float* src = x + (size_t)tok * 2048 + kh;
    u16* dst = At + (size_t)poff[e] * 2048 + (size_t)bm * (128 * 2048) + row * 32 + kh;
#pragma unroll 4
    for (int kb = 0; kb < 64; ++kb) {
        const float* s = src + kb * 32;
        float4 f0 = *reinterpret_cast<const float4*>(s);
        float4 f1 = *reinterpret_cast<const float4*>(s + 4);
        float4 f2 = *reinterpret_cast<const float4*>(s + 8);
        float4 f3 = *reinterpret_cast<const float4*>(s + 12);
        bf16x8 v0, v1;
        v0[0] = (__bf16)f0.x; v0[1] = (__bf16)f0.y; v0[2] = (__bf16)f0.z; v0[3] = (__bf16)f0.w;
        v0[4] = (__bf16)f1.x; v0[5] = (__bf16)f1.y; v0[6] = (__bf16)f1.z; v0[7] = (__bf16)f1.w;
        v1[0] = (__bf16)f2.x; v1[1] = (__bf16)f2.y; v1[2] = (__bf16)f2.z; v1[3] = (__bf16)f2.w;
        v1[4] = (__bf16)f3.x; v1[5] = (__bf16)f3.y; v1[6] = (__bf16)f3.z; v1[7] = (__bf16)f3.w;
        u16* d = dst + (size_t)kb * 4096;
        *reinterpret_cast<bf16x8*>(d) = v0;
        *reinterpret_cast<bf16x8*>(d + 8) = v1;
    }
}

// ---------------- GEMM1: H = silu(A*Wg)*(A*Wu); tiled operands, dbuf pipeline ----------------
template <bool GATHER, int KK, int NN, int NBN>
__global__ __launch_bounds__(256, 2) void ffn_in_kernel(
    const u16* __restrict__ At, const u16* __restrict__ BgT, const u16* __restrict__ BuT,
    u16* __restrict__ Hout,
    const int* __restrict__ counts, const int* __restrict__ ids, const int* __restrict__ poff,
    int Mshared) {
    __shared__ u16 Alds[2 * 4096];
    __shared__ u16 Bglds[2 * 4096];
    __shared__ u16 Bulds[2 * 4096];

    int bm, bn, e;
    if (GATHER) {
        // XCD-chunked swizzle: each XCD owns NEXP/8 experts' full panel set
        int lin = blockIdx.x + 32 * (blockIdx.y + NBN * blockIdx.z);
        int xcd = lin & 7, j = lin >> 3;
        constexpr int SLOTS = 32 * NBN;
        e = xcd * (NEXP / 8) + j / SLOTS;
        int slot = j % SLOTS;
        bn = slot >> 5; bm = slot & 31;
    } else {
        bm = blockIdx.x; bn = blockIdx.y; e = 0;
    }

    int M, hrowbase;
    const u16 *a0, *bg0, *bu0;
    if (GATHER) {
        M = counts[e];
        if (bm * 128 >= M) return;
        a0 = At + (size_t)poff[e] * KK;
        hrowbase = poff[e];
        bg0 = BgT + (size_t)e * NN * KK;
        bu0 = BuT + (size_t)e * NN * KK;
    } else {
        M = Mshared; hrowbase = 0; a0 = At; bg0 = BgT; bu0 = BuT;
        if (bm * 128 >= M) return;
    }
    const int tid = threadIdx.x, lane = tid & 63, wid = tid >> 6;
    const size_t aTile = (size_t)bm * (128 * KK);
    const size_t bTile = (size_t)bn * (128 * KK);
    const int ci0 = wid * 2, l8 = lane * 8;
    const int wr = wid >> 1, wc = wid & 1;
    const int l15 = lane & 15, lk = lane >> 4;

    f32x4 accg[4][4], accu[4][4];
#pragma unroll
    for (int m = 0; m < 4; ++m)
#pragma unroll
        for (int n = 0; n < 4; ++n) {
            accg[m][n] = {0.f, 0.f, 0.f, 0.f};
            accu[m][n] = {0.f, 0.f, 0.f, 0.f};
        }

    auto STAGE = [&](int kb, int buf) {
        const size_t so = (size_t)kb * 4096;
#pragma unroll
        for (int i = 0; i < 2; ++i) {
            const int co = (ci0 + i) * 512 + l8;
            const int lo = buf * 4096 + co;
            glds16(a0 + aTile + so + co, &Alds[lo]);
            glds16(bg0 + bTile + so + co, &Bglds[lo]);
            glds16(bu0 + bTile + so + co, &Bulds[lo]);
        }
    };
    auto COMPUTE = [&](int buf) {
        bf16x8 a[4], bg[4], bu[4];
#pragma unroll
        for (int m = 0; m < 4; ++m) a[m] = *reinterpret_cast<const bf16x8*>(&Alds[buf * 4096 + (wr * 64 + m * 16 + l15) * 32 + lk * 8]);
#pragma unroll
        for (int n = 0; n < 4; ++n) bg[n] = *reinterpret_cast<const bf16x8*>(&Bglds[buf * 4096 + (wc * 64 + n * 16 + l15) * 32 + lk * 8]);
#pragma unroll
        for (int n = 0; n < 4; ++n) bu[n] = *reinterpret_cast<const bf16x8*>(&Bulds[buf * 4096 + (wc * 64 + n * 16 + l15) * 32 + lk * 8]);
#pragma unroll
        for (int m = 0; m < 4; ++m)
#pragma unroll
            for (int n = 0; n < 4; ++n) {
                accg[m][n] = __builtin_amdgcn_mfma_f32_16x16x32_bf16(a[m], bg[n], accg[m][n], 0, 0, 0);
                accu[m][n] = __builtin_amdgcn_mfma_f32_16x16x32_bf16(a[m], bu[n], accu[m][n], 0, 0, 0);
            }
    };

    constexpr int NKB = KK / 32;
    STAGE(0, 0);
    asm volatile("s_waitcnt vmcnt(0)" ::: "memory");
    __builtin_amdgcn_s_barrier();
    int cur = 0;
#pragma unroll 1
    for (int kb = 0; kb < NKB - 1; ++kb) {
        STAGE(kb + 1, cur ^ 1);
        COMPUTE(cur);
        asm volatile("s_waitcnt vmcnt(0)" ::: "memory");
        __builtin_amdgcn_s_barrier();
        __builtin_amdgcn_sched_barrier(0);
        cur ^= 1;
    }
    COMPUTE(cur);

    // epilogue: h = silu(g)*u -> H tiled (write all rows incl. padding; finite via clamped toks)
#pragma unroll
    for (int m = 0; m < 4; ++m) {
#pragma unroll
        for (int r = 0; r < 4; ++r) {
            int rowl = wr * 64 + m * 16 + lk * 4 + r;
#pragma unroll
            for (int n = 0; n < 4; ++n) {
                float g = accg[m][n][r], u = accu[m][n][r];
                float h = g / (1.f + __expf(-g)) * u;
                int col = bn * 128 + wc * 64 + n * 16 + l15;
                size_t hd = ((size_t)hrowbase + bm * 128) * NN + (size_t)(col >> 5) * 4096 + rowl * 32 + (col & 31);
                __bf16 hb = (__bf16)h;
                Hout[hd] = __builtin_bit_cast(u16, hb);
            }
        }
    }
}

// ---------------- GEMM2: Y = H * Wd; tiled operands, dbuf pipeline ----------------
template <bool ATOMIC, int KK, int NN, int NBN>
__global__ __launch_bounds__(256, 2) void ffn_out_kernel(
    const u16* __restrict__ Hbase, const u16* __restrict__ BdT, float* __restrict__ out,
    const int* __restrict__ counts, const int* __restrict__ ids, const int* __restrict__ poff,
    const float* __restrict__ wgts, int Mshared) {
    __shared__ u16 Alds[2 * 4096];
    __shared__ u16 Blds[2 * 4096];

    int bm, bn, e;
    if (ATOMIC) {
        int lin = blockIdx.x + 32 * (blockIdx.y + NBN * blockIdx.z);
        int xcd = lin & 7, j = lin >> 3;
        constexpr int SLOTS = 32 * NBN;
        e = xcd * (NEXP / 8) + j / SLOTS;
        int slot = j % SLOTS;
        bn = slot >> 5; bm = slot & 31;
    } else {
        bm = blockIdx.x; bn = blockIdx.y; e = 0;
    }

    int M;
    const u16 *a0, *b0;
    if (ATOMIC) {
        M = counts[e];
        if (bm * 128 >= M) return;
        a0 = Hbase + (size_t)poff[e] * KK;
        b0 = BdT + (size_t)e * NN * KK;
    } else {
        M = Mshared; a0 = Hbase; b0 = BdT;
        if (bm * 128 >= M) return;
    }
    const int tid = threadIdx.x, lane = tid & 63, wid = tid >> 6;
    const size_t aTile = (size_t)bm * (128 * KK);
    const size_t bTile = (size_t)bn * (128 * KK);
    const int ci0 = wid * 2, l8 = lane * 8;
    const int wr = wid >> 1, wc = wid & 1;
    const int l15 = lane & 15, lk = lane >> 4;

    f32x4 acc[4][4];
#pragma unroll
    for (int m = 0; m < 4; ++m)
#pragma unroll
        for (int n = 0; n < 4; ++n) acc[m][n] = {0.f, 0.f, 0.f, 0.f};

    auto STAGE = [&](int kb, int buf) {
        const size_t so = (size_t)kb * 4096;
#pragma unroll
        for (int i = 0; i < 2; ++i) {
            const int co = (ci0 + i) * 512 + l8;
            const int lo = buf * 4096 + co;
            glds16(a0 + aTile + so + co, &Alds[lo]);
            glds16(b0 + bTile + so + co, &Blds[lo]);
        }
    };
    auto COMPUTE = [&](int buf) {
        bf16x8 a[4], b[4];
#pragma unroll
        for (int m = 0; m < 4; ++m) a[m] = *reinterpret_cast<const bf16x8*>(&Alds[buf * 4096 + (wr * 64 + m * 16 + l15) * 32 + lk * 8]);
#pragma unroll
        for (int n = 0; n < 4; ++n) b[n] = *reinterpret_cast<const bf16x8*>(&Blds[buf * 4096 + (wc * 64 + n * 16 + l15) * 32 + lk * 8]);
#pragma unroll
        for (int m = 0; m < 4; ++m)
#pragma unroll
            for (int n = 0; n < 4; ++n)
                acc[m][n] = __builtin_amdgcn_mfma_f32_16x16x32_bf16(a[m], b[n], acc[m][n], 0, 0, 0);
    };

    constexpr int NKB = KK / 32;
    STAGE(0, 0);
    asm volatile("s_waitcnt vmcnt(0)" ::: "memory");
    __builtin_amdgcn_s_barrier();
    int cur = 0;
#pragma unroll 1
    for (int kb = 0; kb < NKB - 1; ++kb) {
        STAGE(kb + 1, cur ^ 1);
        COMPUTE(cur);
        asm volatile("s_waitcnt vmcnt(0)" ::: "memory");
        __builtin_amdgcn_s_barrier();
        __builtin_amdgcn_sched_barrier(0);
        cur ^= 1;
    }
    COMPUTE(cur);

#pragma unroll
    for (int m = 0; m < 4; ++m) {
#pragma unroll
        for (int r = 0; r < 4; ++r) {
            int rowl = wr * 64 + m * 16 + lk * 4 + r;
            int grow = bm * 128 + rowl;
            if (grow < M) {
                if (ATOMIC) {
                    int tok = ids[e * T_TOK + grow];
                    float w = wgts[e * T_TOK + grow];
#pragma unroll
                    for (int n = 0; n < 4; ++n) {
                        int col = bn * 128 + wc * 64 + n * 16 + l15;
                        atomicAdd(&out[(size_t)tok * NN + col], acc[m][n][r] * w);
                    }
                } else {
#pragma unroll
                    for (int n = 0; n < 4; ++n) {
                        int col = bn * 128 + wc * 64 + n * 16 + l15;
                        out[(size_t)grow * NN + col] = acc[m][n][r];
                    }
                }
            }
        }
    }
}

extern "C" void kernel_launch(void* const* d_in, const int* in_sizes, int n_in,
                              void* d_out, int out_size, void* d_ws, size_t ws_size,
                              hipStream_t stream) {
    const float* x = (const float*)d_in[0];
    const float* gate_w = (const float*)d_in[1];
    const float* wg = (const float*)d_in[2];
    const float* wu = (const float*)d_in[3];
    const float* wd = (const float*)d_in[4];
    const float* swg = (const float*)d_in[5];
    const float* swu = (const float*)d_in[6];
    const float* swd = (const float*)d_in[7];
    float* out = (float*)d_out;

    char* ws = (char*)d_ws;
    size_t off = 0;
    auto alloc = [&](size_t bytes) {
        void* p = ws + off;
        off = (off + bytes + 255) & ~(size_t)255;
        return p;
    };
    u16* xbT = (u16*)alloc((size_t)T_TOK * DIMK * 2);                 // 16.8 MB (tiled)
    u16* At = (u16*)alloc((size_t)MAXPADROWS * DIMK * 2);             // 117.4 MB (tiled, padded)
    u16* H = (u16*)alloc((size_t)MAXPADROWS * INTERN * 2);            // 58.7 MB (tiled, padded)
    int* ids = (int*)alloc((size_t)NEXP * T_TOK * 4);
    float* wgts = (float*)alloc((size_t)NEXP * T_TOK * 4);
    int* counts = (int*)alloc(NEXP * 4);
    int* poff = (int*)alloc(NEXP * 4);
    u16* swgT = (u16*)alloc((size_t)SINTER * DIMK * 2);               // 8.4 MB
    u16* swuT = (u16*)alloc((size_t)SINTER * DIMK * 2);               // 8.4 MB
    u16* swdT = (u16*)alloc((size_t)DIMK * SINTER * 2);               // 8.4 MB
    u16* wgT = (u16*)alloc((size_t)NEXP * INTERN * DIMK * 2);         // 134 MB
    u16* wuT = (u16*)alloc((size_t)NEXP * INTERN * DIMK * 2);         // 134 MB
    u16* wdT = wgT;            // alias: transposed after eGEMM1 consumed wgT
    u16* Hs = At;              // alias: shared-H (16.8MB) written after eGEMM1 consumed At

    hipMemsetAsync(counts, 0, NEXP * 4, stream);
    cast_x_tiled_kernel<<<(T_TOK * DIMK) / (256 * 8), 256, 0, stream>>>(x, xbT);
    gate_kernel<<<T_TOK, 64, 0, stream>>>(x, gate_w, counts, ids, wgts);
    scan_kernel<<<1, 64, 0, stream>>>(counts, poff);
    gather_a_kernel<<<dim3(32, NEXP), 256, 0, stream>>>(x, ids, counts, poff, At);

    // weight transpose+convert into tiled bf16 layouts
    transpose_cvt_tiled_kernel<DIMK, SINTER><<<dim3(SINTER / 64, DIMK / 64, 1), 256, 0, stream>>>(swg, swgT);
    transpose_cvt_tiled_kernel<DIMK, SINTER><<<dim3(SINTER / 64, DIMK / 64, 1), 256, 0, stream>>>(swu, swuT);
    transpose_cvt_tiled_kernel<SINTER, DIMK><<<dim3(DIMK / 64, SINTER / 64, 1), 256, 0, stream>>>(swd, swdT);
    transpose_cvt_tiled_kernel<DIMK, INTERN><<<dim3(INTERN / 64, DIMK / 64, NEXP), 256, 0, stream>>>(wg, wgT);
    transpose_cvt_tiled_kernel<DIMK, INTERN><<<dim3(INTERN / 64, DIMK / 64, NEXP), 256, 0, stream>>>(wu, wuT);

    // expert GEMM1 (gather + fused silu*up): K=2048, N=1024
    ffn_in_kernel<true, DIMK, INTERN, 8><<<dim3(32, 8, NEXP), 256, 0, stream>>>(
        At, wgT, wuT, H, counts, ids, poff, 0);
    // shared GEMM1: K=2048, N=2048 (Hs aliases At — runs after eGEMM1)
    ffn_in_kernel<false, DIMK, SINTER, 16><<<dim3(32, 16, 1), 256, 0, stream>>>(
        xbT, swgT, swuT, Hs, nullptr, nullptr, nullptr, T_TOK);

    // wd transpose into aliased wgT region (after eGEMM1)
    transpose_cvt_tiled_kernel<INTERN, DIMK><<<dim3(DIMK / 64, INTERN / 64, NEXP), 256, 0, stream>>>(wd, wdT);

    // shared GEMM2 writes d_out (full overwrite): K=2048, N=2048
    ffn_out_kernel<false, SINTER, DIMK, 16><<<dim3(32, 16, 1), 256, 0, stream>>>(
        Hs, swdT, out, nullptr, nullptr, nullptr, nullptr, T_TOK);
    // expert GEMM2 atomic-accumulates: K=1024, N=2048
    ffn_out_kernel<true, INTERN, DIMK, 16><<<dim3(32, 16, NEXP), 256, 0, stream>>>(
        H, wdT, out, counts, ids, poff, wgts, 0);
}